// Round 5
// baseline (117.263 us; speedup 1.0000x reference)
//
#include <hip/hip_runtime.h>
#include <hip/hip_bf16.h>

// Problem dims (fixed by reference)
#define BB 8
#define NN 96
#define DD 512
#define EE 4
#define ROWS (BB * NN)          // 768

typedef __attribute__((ext_vector_type(8))) short s8v;   // 8 bf16 = 4 VGPRs
typedef __attribute__((ext_vector_type(4))) short s4v;
typedef __attribute__((ext_vector_type(4))) float f32x4;

// ---------------- ws layout (flat; ws = 256 MiB) ----------------
#define WS_EW      4096                 // f32 [8][512]        = 16,384
#define WS_PN      20480                // f32 [768][8]        = 24,576
#define WS_S1      45056                // f32 [2][768]        = 6,144
#define WS_UH      51200                // bf16 [2][768][2048] = 6,291,456
#define WS_ACAT    6342656              // bf16 [768][1536]    = 2,359,296
#define WS_EDGEST  8701952              // bf16 [8][512][512]  = 4,194,304
#define WS_WT      12896256             // bf16 [3][512][1536] = 4,718,592
#define WS_RN      17614848             // bf16 [768][512]     = 786,432
#define WS_ZB      18401280             // f32  [768][512]     = 1,572,864
#define WS_HPRE    19974144             // f32  [768][512]     = 1,572,864

__device__ __forceinline__ short f2bf(float x) {   // RNE f32->bf16
  unsigned int u = __builtin_bit_cast(unsigned int, x);
  u += 0x7FFFu + ((u >> 16) & 1u);
  return (short)(u >> 16);
}
__device__ __forceinline__ float b2f(short s) {
  unsigned int u = ((unsigned int)(unsigned short)s) << 16;
  return __builtin_bit_cast(float, u);
}

__device__ __forceinline__ f32x4 mfma16(s8v a, s8v b, f32x4 c) {
  asm("v_mfma_f32_16x16x32_bf16 %0, %1, %2, %0" : "+v"(c) : "v"(a), "v"(b));
  return c;
}

__device__ __forceinline__ int get_exist(const void* p, int code, int idx) {
  switch (code) {
    case 0: return ((const unsigned char*)p)[idx] != 0;
    case 1: return ((const int*)p)[idx] != 0;
    case 2: return ((const float*)p)[idx] != 0.0f;
    default: return ((const long long*)p)[idx] != 0;
  }
}

// ---------------- merged prep: transposes (z=0..10) + detect/ew (z=11) ----------------
// z 0..7: edges[z] [512][512] -> edgesT (bf16, [n][k])
// z 8..10: Wr/Wz/Wh [1536][512] -> WT (bf16, [n][k])
// z 11: y=0,1 (x==0): exist-encoding detect;  y=2..9: ew[de] = edges[de] @ wa2
__global__ __launch_bounds__(256) void k_tr_all(const float* __restrict__ edges,
                                                const float* __restrict__ Wr,
                                                const float* __restrict__ Wz,
                                                const float* __restrict__ Wh,
                                                const float* __restrict__ Wa_in,
                                                const float* __restrict__ Wa_out,
                                                const void* exist_in,
                                                const void* exist_out,
                                                short* __restrict__ edgesT,
                                                short* __restrict__ WT,
                                                float* __restrict__ ew,
                                                int* __restrict__ flags) {
  __shared__ float t[32][33];
  __shared__ int red[3];
  int z = blockIdx.z;
  if (z == 11) {
    int tt = threadIdx.x;
    if (blockIdx.y < 2) {                       // ---- detect ----
      if (blockIdx.x) return;
      if (tt < 3) red[tt] = 0;
      __syncthreads();
      const uint4* p = (const uint4*)(blockIdx.y ? exist_out : exist_in);
      int mis = 0, gt = 0, od = 0;
      for (int i = tt; i < 4608; i += 256) {    // first 73728 bytes
        uint4 v = p[i];
        unsigned any = v.x | v.y | v.z | v.w;
        if (any) {
          if (any & 0xFFFFFF00u) mis = 1;
          if (any & 0xFEFEFEFEu) gt = 1;
          if (v.y | v.w) od = 1;
        }
      }
      if (mis) atomicOr(&red[0], 1);
      if (gt) atomicOr(&red[1], 1);
      if (od) atomicOr(&red[2], 1);
      __syncthreads();
      if (tt == 0) flags[blockIdx.y] = red[0] ? (red[1] ? 2 : 0) : (red[2] ? 1 : 3);
    } else if (blockIdx.y < 10) {               // ---- ew[de][k] = edges[de][k][:] . wa2 ----
      int de = blockIdx.y - 2;
      int dir = de >> 2;
      const float* wa2 = (dir ? Wa_out : Wa_in) + DD;
      int wv = tt >> 6, lane = tt & 63;
      int k = blockIdx.x * 32 + wv * 8;
      for (int rr = 0; rr < 8; ++rr, ++k) {
        const float* er = edges + ((size_t)de * DD + k) * DD;
        float acc = 0.f;
        for (int i = lane; i < DD; i += 64) acc = fmaf(er[i], wa2[i], acc);
#pragma unroll
        for (int off = 32; off; off >>= 1) acc += __shfl_xor(acc, off);
        if (lane == 0) ew[de * DD + k] = acc;
      }
    }
    return;
  }
  const float* src;
  short* dst;
  int dstPitch;
  if (z < 8) {
    if (blockIdx.y >= 16) return;               // edges: 512 rows only
    src = edges + (size_t)z * DD * DD;
    dst = edgesT + (size_t)z * DD * DD;
    dstPitch = DD;
  } else {
    int w = z - 8;
    src = w == 0 ? Wr : (w == 1 ? Wz : Wh);
    dst = WT + (size_t)w * (512 * 1536);
    dstPitch = 1536;
  }
  int r0 = blockIdx.y * 32, c0 = blockIdx.x * 32;
  int row = threadIdx.x >> 3, c4 = (threadIdx.x & 7) * 4;
  float4 v = *(const float4*)(src + (size_t)(r0 + row) * DD + c0 + c4);
  t[row][c4] = v.x; t[row][c4 + 1] = v.y; t[row][c4 + 2] = v.z; t[row][c4 + 3] = v.w;
  __syncthreads();
  s4v o;
  o[0] = f2bf(t[c4 + 0][row]); o[1] = f2bf(t[c4 + 1][row]);
  o[2] = f2bf(t[c4 + 2][row]); o[3] = f2bf(t[c4 + 3][row]);
  *(s4v*)(dst + (size_t)(c0 + row) * dstPitch + r0 + c4) = o;
}

// ---------------- per-row precompute: pn[row][8], s1[2][768], nodes->Acat ----------------
// one wave per row (4 rows / block)
__global__ __launch_bounds__(256) void k_pn(const float* __restrict__ nodes,
                                            const float* __restrict__ ew,
                                            const float* __restrict__ Wa_in,
                                            const float* __restrict__ ba_in,
                                            const float* __restrict__ Wa_out,
                                            const float* __restrict__ ba_out,
                                            float* __restrict__ pn,
                                            float* __restrict__ s1,
                                            short* __restrict__ AcatH) {
  int wv = threadIdx.x >> 6, lane = threadIdx.x & 63;
  int r = blockIdx.x * 4 + wv;
  const float* nrow = nodes + (size_t)r * DD;
  float4 a = *(const float4*)(nrow + lane * 8);
  float4 b = *(const float4*)(nrow + lane * 8 + 4);
  float nf[8] = {a.x, a.y, a.z, a.w, b.x, b.y, b.z, b.w};
  // nodes -> Acat region 2 (bf16)
  s8v h;
#pragma unroll
  for (int i = 0; i < 8; ++i) h[i] = f2bf(nf[i]);
  *(s8v*)&AcatH[(size_t)r * 1536 + 1024 + lane * 8] = h;
  // pn dots
#pragma unroll
  for (int de = 0; de < 8; ++de) {
    const float* e = ew + de * DD + lane * 8;
    float p = 0.f;
#pragma unroll
    for (int i = 0; i < 8; ++i) p = fmaf(nf[i], e[i], p);
#pragma unroll
    for (int off = 32; off; off >>= 1) p += __shfl_xor(p, off);
    if (lane == 0) pn[r * 8 + de] = p;
  }
  // s1 dots (wa[0:512]) + bias
#pragma unroll
  for (int dir = 0; dir < 2; ++dir) {
    const float* wa = (dir ? Wa_out : Wa_in) + lane * 8;
    float p = 0.f;
#pragma unroll
    for (int i = 0; i < 8; ++i) p = fmaf(nf[i], wa[i], p);
#pragma unroll
    for (int off = 32; off; off >>= 1) p += __shfl_xor(p, off);
    if (lane == 0) s1[dir * ROWS + r] = p + (dir ? ba_out[0] : ba_in[0]);
  }
}

// ---------------- attention: softmax + per-edge-type aggregation of nodes ----------------
// block = (dir, b, i); writes UH[dir][row][e*512+h]
__global__ __launch_bounds__(256) void k_attn(const float* __restrict__ pn,
                                              const float* __restrict__ s1,
                                              const int* __restrict__ adj_in,
                                              const int* __restrict__ adj_out,
                                              const void* exist_in,
                                              const void* exist_out,
                                              const int* __restrict__ fr,
                                              const float* __restrict__ nodes,
                                              short* __restrict__ UH) {
  __shared__ float s_w[NN];
  __shared__ int s_tj[NN];
  __shared__ int s_ex[NN];
  __shared__ float s_inv;
  int blk = blockIdx.x;
  int dir = blk / ROWS;
  int row = blk % ROWS;
  int b = row / NN;
  const int* adj = dir ? adj_out : adj_in;
  const void* ex = dir ? exist_out : exist_in;
  int code = fr[dir];
  int t = threadIdx.x;
  float s1v = s1[dir * ROWS + row];
  if (t < NN) {
    int idx = row * NN + t;
    int e_ = get_exist(ex, code, idx);
    int tj = adj[idx];
    s_ex[t] = e_;
    s_tj[t] = tj;
    float sc = -1e9f;
    if (e_) {
      float x = s1v + pn[(b * NN + t) * 8 + dir * 4 + tj];
      sc = x >= 0.f ? x : 0.2f * x;
    }
    s_w[t] = sc;
  }
  __syncthreads();
  // softmax over 96 slots on wave 0
  if (t < 64) {
    float e1 = s_w[t];
    float e2 = (t < 32) ? s_w[t + 64] : -1e30f;
    float mx = fmaxf(e1, e2);
#pragma unroll
    for (int off = 32; off; off >>= 1) mx = fmaxf(mx, __shfl_xor(mx, off));
    float w1 = s_ex[t] ? __expf(e1 - mx) : 0.f;
    float w2 = (t < 32 && s_ex[t + 64]) ? __expf(e2 - mx) : 0.f;
    s_w[t] = w1;
    if (t < 32) s_w[t + 64] = w2;
    float sm = w1 + w2;
#pragma unroll
    for (int off = 32; off; off >>= 1) sm += __shfl_xor(sm, off);
    if (t == 0) s_inv = 1.f / sm;
  }
  __syncthreads();
  float inv = s_inv;
  // aggregate weighted node rows into 4 edge-type buckets
  float accA[4] = {}, accB[4] = {};
  int h0 = t, h1 = t + 256;
  for (int j = 0; j < NN; ++j) {
    if (s_ex[j]) {
      float wj = s_w[j];
      int ej = s_tj[j];
      const float* np = nodes + (size_t)(b * NN + j) * DD;
      float v0 = np[h0], v1 = np[h1];
#pragma unroll
      for (int e = 0; e < 4; ++e) {
        float we = (ej == e) ? wj : 0.f;
        accA[e] = fmaf(we, v0, accA[e]);
        accB[e] = fmaf(we, v1, accB[e]);
      }
    }
  }
  size_t ub = (size_t)(dir * ROWS + row) * 2048;
#pragma unroll
  for (int e = 0; e < 4; ++e) {
    UH[ub + e * 512 + h0] = f2bf(accA[e] * inv);
    UH[ub + e * 512 + h1] = f2bf(accB[e] * inv);
  }
}

// ---------------- staging + MFMA tile helpers ----------------
__device__ __forceinline__ void stage_bf(const short* __restrict__ src, int pitch,
                                         short* lds, int tid) {
  int row = tid >> 2, cc = (tid & 3) * 16;
  const short* p = src + (size_t)row * pitch + cc;
  s8v h0 = *(const s8v*)p;
  s8v h1 = *(const s8v*)(p + 8);
  *(s8v*)&lds[row * 72 + cc] = h0;
  *(s8v*)&lds[row * 72 + cc + 8] = h1;
}

__device__ __forceinline__ void mfma_tile(const short* As, const short* Bs,
                                          int wr, int wc, int l, f32x4 acc[2][2]) {
  int lr = l & 15, lg = l >> 4;
#pragma unroll
  for (int ks = 0; ks < 64; ks += 32) {
    s8v a0 = *(const s8v*)&As[(wr + lr) * 72 + ks + 8 * lg];
    s8v a1 = *(const s8v*)&As[(wr + 16 + lr) * 72 + ks + 8 * lg];
    s8v b0 = *(const s8v*)&Bs[(wc + lr) * 72 + ks + 8 * lg];
    s8v b1 = *(const s8v*)&Bs[(wc + 16 + lr) * 72 + ks + 8 * lg];
    acc[0][0] = mfma16(a0, b0, acc[0][0]);
    acc[0][1] = mfma16(a0, b1, acc[0][1]);
    acc[1][0] = mfma16(a1, b0, acc[1][0]);
    acc[1][1] = mfma16(a1, b1, acc[1][1]);
  }
}

// ---------------- GEMM U: Acat[:, dir*512+n] = U[dir] @ stackedW ----------------
// B[k=e*512+h'][n] = edges[dir][e][h'][n] = edgesT[dir*4+e][n][h']
__global__ __launch_bounds__(256) void k_gemm_u(const short* __restrict__ UH,
                                                const short* __restrict__ edgesT,
                                                short* __restrict__ AcatH) {
  __shared__ __align__(16) short As[64 * 72];
  __shared__ __align__(16) short Bs[64 * 72];
  int tid = threadIdx.x;
  int dir = blockIdx.z;
  int row0 = blockIdx.y * 64;
  int n0 = blockIdx.x * 64;          // [0,512)
  const short* Asrc = UH + (size_t)(dir * ROWS + row0) * 2048;
  int w = tid >> 6, l = tid & 63;
  int wr = (w >> 1) * 32, wc = (w & 1) * 32;
  f32x4 acc[2][2] = {};
  for (int k0 = 0; k0 < 2048; k0 += 64) {
    int e = k0 >> 9, hp = k0 & 511;
    stage_bf(Asrc + k0, 2048, As, tid);
    stage_bf(edgesT + (size_t)(dir * 4 + e) * DD * DD + (size_t)n0 * DD + hp, DD,
             Bs, tid);
    __syncthreads();
    mfma_tile(As, Bs, wr, wc, l, acc);
    __syncthreads();
  }
  asm volatile("s_nop 7\n\ts_nop 7");
  int lr = l & 15, lg4 = (l >> 4) * 4;
#pragma unroll
  for (int fi = 0; fi < 2; ++fi)
#pragma unroll
    for (int fj = 0; fj < 2; ++fj) {
      f32x4 v = acc[fi][fj];
#pragma unroll
      for (int r = 0; r < 4; ++r) {
        int row = row0 + wr + fi * 16 + lg4 + r;
        int c = n0 + wc + fj * 16 + lr;
        AcatH[(size_t)row * 1536 + dir * 512 + c] = f2bf(v[r]);
      }
    }
}

// ---------------- GEMM1: AcatH[768,1536] @ {WrT|WzT|WhT[:,:1024]} + epilogue ----------------
__global__ __launch_bounds__(256) void k_gemm1(const short* __restrict__ AcatH,
                                               const short* __restrict__ WT,
                                               const float* __restrict__ br,
                                               const float* __restrict__ bz,
                                               const float* __restrict__ nodes,
                                               short* __restrict__ rnH,
                                               float* __restrict__ zb,
                                               float* __restrict__ Hpre) {
  __shared__ __align__(16) short As[64 * 72];
  __shared__ __align__(16) short Bs[64 * 72];
  int tid = threadIdx.x;
  int row0 = blockIdx.y * 64;
  int col0 = blockIdx.x * 64;           // [0,1536)
  int region = col0 >> 9, c0 = col0 & 511;
  int K = (region == 2) ? 1024 : 1536;
  const short* Bsrc = WT + (size_t)region * (512 * 1536) + (size_t)c0 * 1536;
  const short* Asrc = AcatH + (size_t)row0 * 1536;
  int w = tid >> 6, l = tid & 63;
  int wr = (w >> 1) * 32, wc = (w & 1) * 32;
  f32x4 acc[2][2] = {};
  for (int k0 = 0; k0 < K; k0 += 64) {
    stage_bf(Asrc + k0, 1536, As, tid);
    stage_bf(Bsrc + k0, 1536, Bs, tid);
    __syncthreads();
    mfma_tile(As, Bs, wr, wc, l, acc);
    __syncthreads();
  }
  asm volatile("s_nop 7\n\ts_nop 7");
  int lr = l & 15, lg4 = (l >> 4) * 4;
#pragma unroll
  for (int fi = 0; fi < 2; ++fi)
#pragma unroll
    for (int fj = 0; fj < 2; ++fj) {
      f32x4 v = acc[fi][fj];
#pragma unroll
      for (int r = 0; r < 4; ++r) {
        int row = row0 + wr + fi * 16 + lg4 + r;
        int c = c0 + wc + fj * 16 + lr;
        float vv = v[r];
        size_t o = (size_t)row * DD + c;
        if (region == 0) {
          float s = 1.f / (1.f + __expf(-(vv + br[c])));
          rnH[o] = f2bf(s * nodes[o]);
        } else if (region == 1) {
          zb[o] = 1.f / (1.f + __expf(-(vv + bz[c])));
        } else {
          Hpre[o] = vv;
        }
      }
    }
}

// ---------------- GEMM2: rn @ WhT[:,1024:] + final gate ----------------
__global__ __launch_bounds__(256) void k_gemm2(const short* __restrict__ rnH,
                                               const short* __restrict__ WT,
                                               const float* __restrict__ bh,
                                               const float* __restrict__ Hpre,
                                               const float* __restrict__ zb,
                                               const float* __restrict__ nodes,
                                               float* __restrict__ out) {
  __shared__ __align__(16) short As[64 * 72];
  __shared__ __align__(16) short Bs[64 * 72];
  int tid = threadIdx.x;
  int row0 = blockIdx.y * 64;
  int col0 = blockIdx.x * 64;           // [0,512)
  const short* Bsrc = WT + (size_t)2 * (512 * 1536) + (size_t)col0 * 1536 + 1024;
  const short* Asrc = rnH + (size_t)row0 * DD;
  int w = tid >> 6, l = tid & 63;
  int wr = (w >> 1) * 32, wc = (w & 1) * 32;
  f32x4 acc[2][2] = {};
  for (int k0 = 0; k0 < DD; k0 += 64) {
    stage_bf(Asrc + k0, DD, As, tid);
    stage_bf(Bsrc + k0, 1536, Bs, tid);
    __syncthreads();
    mfma_tile(As, Bs, wr, wc, l, acc);
    __syncthreads();
  }
  asm volatile("s_nop 7\n\ts_nop 7");
  int lr = l & 15, lg4 = (l >> 4) * 4;
#pragma unroll
  for (int fi = 0; fi < 2; ++fi)
#pragma unroll
    for (int fj = 0; fj < 2; ++fj) {
      f32x4 v = acc[fi][fj];
#pragma unroll
      for (int r = 0; r < 4; ++r) {
        int row = row0 + wr + fi * 16 + lg4 + r;
        int c = col0 + wc + fj * 16 + lr;
        size_t o = (size_t)row * DD + c;
        float h = tanhf(v[r] + Hpre[o] + bh[c]);
        float zz = zb[o];
        float nd = nodes[o];
        out[o] = (1.f - zz) * nd + zz * h;
      }
    }
}

extern "C" void kernel_launch(void* const* d_in, const int* in_sizes, int n_in,
                              void* d_out, int out_size, void* d_ws, size_t ws_size,
                              hipStream_t stream) {
  const float* nodes = (const float*)d_in[0];
  const float* edges = (const float*)d_in[1];
  const int* adj_in = (const int*)d_in[2];
  const int* adj_out = (const int*)d_in[3];
  const void* exist_in = d_in[4];
  const void* exist_out = d_in[5];
  const float* Wa_in = (const float*)d_in[6];
  const float* ba_in = (const float*)d_in[7];
  const float* Wa_out = (const float*)d_in[8];
  const float* ba_out = (const float*)d_in[9];
  const float* Wr = (const float*)d_in[10];
  const float* br = (const float*)d_in[11];
  const float* Wz = (const float*)d_in[12];
  const float* bz = (const float*)d_in[13];
  const float* Wh = (const float*)d_in[14];
  const float* bh = (const float*)d_in[15];

  char* ws = (char*)d_ws;
  int* flags = (int*)ws;
  float* ew = (float*)(ws + WS_EW);
  float* pn = (float*)(ws + WS_PN);
  float* s1 = (float*)(ws + WS_S1);
  short* UH = (short*)(ws + WS_UH);
  short* AcatH = (short*)(ws + WS_ACAT);
  short* edgesT = (short*)(ws + WS_EDGEST);
  short* WT = (short*)(ws + WS_WT);
  short* rnH = (short*)(ws + WS_RN);
  float* zb = (float*)(ws + WS_ZB);
  float* Hpre = (float*)(ws + WS_HPRE);
  float* out = (float*)d_out;

  k_tr_all<<<dim3(16, 48, 12), 256, 0, stream>>>(edges, Wr, Wz, Wh, Wa_in, Wa_out,
                                                 exist_in, exist_out, edgesT, WT,
                                                 ew, flags);
  k_pn<<<192, 256, 0, stream>>>(nodes, ew, Wa_in, ba_in, Wa_out, ba_out, pn, s1,
                                AcatH);
  k_attn<<<2 * ROWS, 256, 0, stream>>>(pn, s1, adj_in, adj_out, exist_in,
                                       exist_out, flags, nodes, UH);
  k_gemm_u<<<dim3(8, 12, 2), 256, 0, stream>>>(UH, edgesT, AcatH);
  k_gemm1<<<dim3(24, 12), 256, 0, stream>>>(AcatH, WT, br, bz, nodes, rnH, zb,
                                            Hpre);
  k_gemm2<<<dim3(8, 12), 256, 0, stream>>>(rnH, WT, bh, Hpre, zb, nodes, out);
}

// Round 6
// 76.322 us; speedup vs baseline: 1.5364x; 1.5364x over previous
//
#include <hip/hip_runtime.h>
#include <hip/hip_bf16.h>

// Problem dims (fixed by reference)
#define BB 8
#define NN 96
#define DD 512
#define EE 4
#define ROWS 768

typedef __attribute__((ext_vector_type(8))) short s8v;   // 8 bf16 = 4 VGPRs
typedef __attribute__((ext_vector_type(4))) short s4v;
typedef __attribute__((ext_vector_type(4))) float f32x4;

// ---------------- ws layout (flat; ws = 256 MiB) ----------------
#define WS_PROJP   4096                 // f32 [8][6144]       = 196,608
#define WS_NODESH  1048576              // bf16 [768][512]     = 786,432
#define WS_ALLMSGS 2097152              // bf16 [8*768][512]   = 6,291,456
#define WS_ACAT    8388608              // bf16 [768][1536]    = 2,359,296
#define WS_EDGEST  10747904             // bf16 [8][512][512]  = 4,194,304
#define WS_WT      14942208             // bf16 [3][512][1536] = 4,718,592
#define WS_RN      19660800             // bf16 [768][512]     = 786,432
#define WS_ZB      20447232             // f32  [768][512]     = 1,572,864
#define WS_HPRE    22020096             // f32  [768][512]     = 1,572,864

__device__ __forceinline__ short f2bf(float x) {   // RNE f32->bf16
  unsigned int u = __builtin_bit_cast(unsigned int, x);
  u += 0x7FFFu + ((u >> 16) & 1u);
  return (short)(u >> 16);
}
__device__ __forceinline__ float b2f(short s) {
  unsigned int u = ((unsigned int)(unsigned short)s) << 16;
  return __builtin_bit_cast(float, u);
}

__device__ __forceinline__ f32x4 mfma16(s8v a, s8v b, f32x4 c) {
  asm("v_mfma_f32_16x16x32_bf16 %0, %1, %2, %0" : "+v"(c) : "v"(a), "v"(b));
  return c;
}

__device__ __forceinline__ int get_exist(const void* p, int code, int idx) {
  switch (code) {
    case 0: return ((const unsigned char*)p)[idx] != 0;
    case 1: return ((const int*)p)[idx] != 0;
    case 2: return ((const float*)p)[idx] != 0.0f;
    default: return ((const long long*)p)[idx] != 0;
  }
}

// ---------------- prep: transposes + detect + nodes->bf16 ----------------
// z 0..7 : edges[z] [512][512] f32 -> edgesT bf16 [n][k]
// z 8..10: Wr/Wz/Wh [1536][512] f32 -> WT bf16 [n][k]
// z 11 (x==0): y 0,1 = exist detect; y 2..13 = nodesH + Acat region2 (64 rows each)
__global__ __launch_bounds__(256) void k_prep(const float* __restrict__ edges,
                                              const float* __restrict__ Wr,
                                              const float* __restrict__ Wz,
                                              const float* __restrict__ Wh,
                                              const float* __restrict__ nodes,
                                              const void* exist_in,
                                              const void* exist_out,
                                              short* __restrict__ edgesT,
                                              short* __restrict__ WT,
                                              short* __restrict__ nodesH,
                                              short* __restrict__ AcatH,
                                              int* __restrict__ flags) {
  __shared__ float t[32][33];
  __shared__ int red[3];
  int z = blockIdx.z;
  if (z == 11) {
    if (blockIdx.x) return;
    int tt = threadIdx.x;
    int y = blockIdx.y;
    if (y < 2) {                                // ---- detect encoding ----
      if (tt < 3) red[tt] = 0;
      __syncthreads();
      const uint4* p = (const uint4*)(y ? exist_out : exist_in);
      int mis = 0, gt = 0, od = 0;
      for (int i = tt; i < 4608; i += 256) {    // first 73728 bytes
        uint4 v = p[i];
        unsigned any = v.x | v.y | v.z | v.w;
        if (any) {
          if (any & 0xFFFFFF00u) mis = 1;
          if (any & 0xFEFEFEFEu) gt = 1;
          if (v.y | v.w) od = 1;
        }
      }
      if (mis) atomicOr(&red[0], 1);
      if (gt) atomicOr(&red[1], 1);
      if (od) atomicOr(&red[2], 1);
      __syncthreads();
      if (tt == 0) flags[y] = red[0] ? (red[1] ? 2 : 0) : (red[2] ? 1 : 3);
    } else if (y < 14) {                        // ---- nodesH + Acat region 2 ----
      int r0 = (y - 2) * 64;
      for (int rr = 0; rr < 64; ++rr) {
        int r = r0 + rr;
        const float* nr = nodes + (size_t)r * DD;
        short v0 = f2bf(nr[tt]), v1 = f2bf(nr[tt + 256]);
        nodesH[(size_t)r * DD + tt] = v0;
        nodesH[(size_t)r * DD + tt + 256] = v1;
        AcatH[(size_t)r * 1536 + 1024 + tt] = v0;
        AcatH[(size_t)r * 1536 + 1024 + tt + 256] = v1;
      }
    }
    return;
  }
  const float* src;
  short* dst;
  int dstPitch;
  if (z < 8) {
    if (blockIdx.y >= 16) return;               // edges: 512 rows only
    src = edges + (size_t)z * DD * DD;
    dst = edgesT + (size_t)z * DD * DD;
    dstPitch = DD;
  } else {
    int w = z - 8;
    src = w == 0 ? Wr : (w == 1 ? Wz : Wh);
    dst = WT + (size_t)w * (512 * 1536);
    dstPitch = 1536;
  }
  int r0 = blockIdx.y * 32, c0 = blockIdx.x * 32;
  int row = threadIdx.x >> 3, c4 = (threadIdx.x & 7) * 4;
  float4 v = *(const float4*)(src + (size_t)(r0 + row) * DD + c0 + c4);
  t[row][c4] = v.x; t[row][c4 + 1] = v.y; t[row][c4 + 2] = v.z; t[row][c4 + 3] = v.w;
  __syncthreads();
  s4v o;
  o[0] = f2bf(t[c4 + 0][row]); o[1] = f2bf(t[c4 + 1][row]);
  o[2] = f2bf(t[c4 + 2][row]); o[3] = f2bf(t[c4 + 3][row]);
  *(s4v*)(dst + (size_t)(c0 + row) * dstPitch + r0 + c4) = o;
}

// ---------------- MFMA tile helper (2x2 16x16 frags per wave, proven) ----------------
__device__ __forceinline__ void mfma_tile(const short* As, const short* Bs,
                                          int wr, int wc, int l, f32x4 acc[2][2]) {
  int lr = l & 15, lg = l >> 4;
#pragma unroll
  for (int ks = 0; ks < 64; ks += 32) {
    s8v a0 = *(const s8v*)&As[(wr + lr) * 72 + ks + 8 * lg];
    s8v a1 = *(const s8v*)&As[(wr + 16 + lr) * 72 + ks + 8 * lg];
    s8v b0 = *(const s8v*)&Bs[(wc + lr) * 72 + ks + 8 * lg];
    s8v b1 = *(const s8v*)&Bs[(wc + 16 + lr) * 72 + ks + 8 * lg];
    acc[0][0] = mfma16(a0, b0, acc[0][0]);
    acc[0][1] = mfma16(a0, b1, acc[0][1]);
    acc[1][0] = mfma16(a1, b0, acc[1][0]);
    acc[1][1] = mfma16(a1, b1, acc[1][1]);
  }
}

// ---------------- GEMM msgs (pipelined) + fused proj partials ----------------
// C[de][m][n] = nodesH[m][:] . edgesT[de][n][:]; projp[chunk][de*768+m] = sum_n C*wa2
__global__ __launch_bounds__(256) void k_gemm_msgs(const short* __restrict__ nodesH,
                                                   const short* __restrict__ edgesT,
                                                   const float* __restrict__ Wa_in,
                                                   const float* __restrict__ Wa_out,
                                                   short* __restrict__ C,
                                                   float* __restrict__ projp) {
  __shared__ __align__(16) short As[64 * 72];
  __shared__ __align__(16) short Bs[64 * 72];
  __shared__ float pp[128];
  int tid = threadIdx.x;
  int row0 = blockIdx.y * 64;
  int col0 = blockIdx.x * 64;        // [0,4096)
  int de = col0 >> 9, h0 = col0 & 511;
  int w = tid >> 6, l = tid & 63;
  int wr = (w >> 1) * 32, wc = (w & 1) * 32;
  int srow = tid >> 2, scc = (tid & 3) * 16;
  const short* Ap = nodesH + (size_t)(row0 + srow) * DD + scc;
  const short* Bp = edgesT + (size_t)de * DD * DD + (size_t)(h0 + srow) * DD + scc;
  s8v a0 = *(const s8v*)Ap, a1 = *(const s8v*)(Ap + 8);
  s8v b0 = *(const s8v*)Bp, b1 = *(const s8v*)(Bp + 8);
  f32x4 acc[2][2] = {};
  for (int k0 = 0; k0 < DD; k0 += 64) {
    *(s8v*)&As[srow * 72 + scc] = a0; *(s8v*)&As[srow * 72 + scc + 8] = a1;
    *(s8v*)&Bs[srow * 72 + scc] = b0; *(s8v*)&Bs[srow * 72 + scc + 8] = b1;
    __syncthreads();
    if (k0 + 64 < DD) {        // prefetch next K-tile into regs (overlaps MFMA)
      Ap += 64; Bp += 64;
      a0 = *(const s8v*)Ap; a1 = *(const s8v*)(Ap + 8);
      b0 = *(const s8v*)Bp; b1 = *(const s8v*)(Bp + 8);
    }
    mfma_tile(As, Bs, wr, wc, l, acc);
    __syncthreads();
  }
  asm volatile("s_nop 7\n\ts_nop 7");   // MFMA->VALU writeback hazard guard
  int lr = l & 15, lg4 = (l >> 4) * 4;
#pragma unroll
  for (int fi = 0; fi < 2; ++fi)
#pragma unroll
    for (int fj = 0; fj < 2; ++fj) {
      f32x4 v = acc[fi][fj];
#pragma unroll
      for (int r = 0; r < 4; ++r) {
        int row = row0 + wr + fi * 16 + lg4 + r;
        int col = h0 + wc + fj * 16 + lr;
        C[((size_t)(de * ROWS + row)) * DD + col] = f2bf(v[r]);
      }
    }
  // ---- fused proj partial: pp[row] = sum over this block's 64 cols of C*wa2 ----
  const float* wa2 = ((de >> 2) ? Wa_out : Wa_in) + DD;
  float w0 = wa2[h0 + wc + lr];
  float w1 = wa2[h0 + wc + 16 + lr];
  float pr[2][4];
#pragma unroll
  for (int fi = 0; fi < 2; ++fi)
#pragma unroll
    for (int r = 0; r < 4; ++r)
      pr[fi][r] = acc[fi][0][r] * w0 + acc[fi][1][r] * w1;
#pragma unroll
  for (int off = 1; off < 16; off <<= 1)
#pragma unroll
    for (int fi = 0; fi < 2; ++fi)
#pragma unroll
      for (int r = 0; r < 4; ++r) pr[fi][r] += __shfl_xor(pr[fi][r], off);
  if (lr == 0) {
#pragma unroll
    for (int fi = 0; fi < 2; ++fi)
#pragma unroll
      for (int r = 0; r < 4; ++r)
        pp[(w & 1) * 64 + wr + fi * 16 + lg4 + r] = pr[fi][r];
  }
  __syncthreads();
  if (tid < 64)
    projp[(size_t)(blockIdx.x & 7) * 6144 + de * ROWS + row0 + tid] =
        pp[tid] + pp[64 + tid];
}

// ---------------- attention (+ fused s1 dot) ----------------
__global__ __launch_bounds__(256) void k_attn(const short* __restrict__ allmsgsH,
                                              const float* __restrict__ projp,
                                              const int* __restrict__ adj_in,
                                              const int* __restrict__ adj_out,
                                              const void* exist_in,
                                              const void* exist_out,
                                              const int* __restrict__ fr,
                                              const float* __restrict__ nodes,
                                              const float* __restrict__ Wa_in,
                                              const float* __restrict__ ba_in,
                                              const float* __restrict__ Wa_out,
                                              const float* __restrict__ ba_out,
                                              short* __restrict__ AcatH) {
  __shared__ float s_w[NN];
  __shared__ int s_tj[NN];
  __shared__ int s_ex[NN];
  __shared__ float s_part[5];
  int blk = blockIdx.x;       // dir*768 + b*96 + i
  int dir = blk / ROWS;
  int row = blk % ROWS;
  int b = row / NN;
  const int* adj = dir ? adj_out : adj_in;
  const void* ex = dir ? exist_out : exist_in;
  int code = fr[dir];
  int t = threadIdx.x, wv = t >> 6, lane = t & 63;
  int h0 = t, h1 = t + 256;
  const float* wa = dir ? Wa_out : Wa_in;
  float nv0 = nodes[(size_t)row * DD + h0];
  float nv1 = nodes[(size_t)row * DD + h1];
  // fused s1 = nodes_row . wa[0:512] (wave shuffle reduce)
  float p = fmaf(nv0, wa[h0], nv1 * wa[h1]);
#pragma unroll
  for (int off = 32; off; off >>= 1) p += __shfl_xor(p, off);
  if (lane == 0) s_part[wv] = p;
  // neighbor metadata
  if (t < NN) {
    int idx = row * NN + t;
    s_ex[t] = get_exist(ex, code, idx);
    s_tj[t] = adj[idx];
  }
  __syncthreads();
  float s1v = s_part[0] + s_part[1] + s_part[2] + s_part[3] +
              (dir ? ba_out[0] : ba_in[0]);
  if (t < NN) {
    float sc = -1e9f;
    if (s_ex[t]) {
      size_t base = (size_t)(dir * 4 + s_tj[t]) * ROWS + b * NN + t;
      float pv = 0.f;
#pragma unroll
      for (int c = 0; c < 8; ++c) pv += projp[(size_t)c * 6144 + base];
      float x = s1v + pv;
      sc = x >= 0.f ? x : 0.2f * x;
    }
    s_w[t] = sc;
  }
  __syncthreads();
  // softmax over 96 slots on wave 0
  if (t < 64) {
    float e1 = s_w[t];
    float e2 = (t < 32) ? s_w[t + 64] : -1e30f;
    float mx = fmaxf(e1, e2);
#pragma unroll
    for (int off = 32; off; off >>= 1) mx = fmaxf(mx, __shfl_xor(mx, off));
    float w1 = s_ex[t] ? __expf(e1 - mx) : 0.f;
    float w2 = (t < 32 && s_ex[t + 64]) ? __expf(e2 - mx) : 0.f;
    s_w[t] = w1;
    if (t < 32) s_w[t + 64] = w2;
    float sm = w1 + w2;
#pragma unroll
    for (int off = 32; off; off >>= 1) sm += __shfl_xor(sm, off);
    if (t == 0) s_part[4] = 1.f / sm;
  }
  __syncthreads();
  float inv = s_part[4];
  float acc0 = 0.f, acc1 = 0.f;
  for (int j = 0; j < NN; ++j) {
    if (s_ex[j]) {
      float wj = s_w[j];
      const short* rp =
          allmsgsH + ((size_t)(dir * EE + s_tj[j]) * ROWS + b * NN + j) * DD;
      acc0 = fmaf(wj, b2f(rp[h0]), acc0);
      acc1 = fmaf(wj, b2f(rp[h1]), acc1);
    }
  }
  short* dst = AcatH + (size_t)row * 1536 + dir * DD;
  dst[h0] = f2bf(acc0 * inv);
  dst[h1] = f2bf(acc1 * inv);
}

// ---------------- GEMM1 (pipelined): AcatH @ {WrT|WzT|WhT[:,:1024]} + epilogue ----------------
__global__ __launch_bounds__(256) void k_gemm1(const short* __restrict__ AcatH,
                                               const short* __restrict__ WT,
                                               const float* __restrict__ br,
                                               const float* __restrict__ bz,
                                               const float* __restrict__ nodes,
                                               short* __restrict__ rnH,
                                               float* __restrict__ zb,
                                               float* __restrict__ Hpre) {
  __shared__ __align__(16) short As[64 * 72];
  __shared__ __align__(16) short Bs[64 * 72];
  int tid = threadIdx.x;
  int row0 = blockIdx.y * 64;
  int col0 = blockIdx.x * 64;           // [0,1536)
  int region = col0 >> 9, c0 = col0 & 511;
  int K = (region == 2) ? 1024 : 1536;
  int w = tid >> 6, l = tid & 63;
  int wr = (w >> 1) * 32, wc = (w & 1) * 32;
  int srow = tid >> 2, scc = (tid & 3) * 16;
  const short* Ap = AcatH + (size_t)(row0 + srow) * 1536 + scc;
  const short* Bp = WT + (size_t)region * (512 * 1536) + (size_t)(c0 + srow) * 1536 + scc;
  s8v a0 = *(const s8v*)Ap, a1 = *(const s8v*)(Ap + 8);
  s8v b0 = *(const s8v*)Bp, b1 = *(const s8v*)(Bp + 8);
  f32x4 acc[2][2] = {};
  for (int k0 = 0; k0 < K; k0 += 64) {
    *(s8v*)&As[srow * 72 + scc] = a0; *(s8v*)&As[srow * 72 + scc + 8] = a1;
    *(s8v*)&Bs[srow * 72 + scc] = b0; *(s8v*)&Bs[srow * 72 + scc + 8] = b1;
    __syncthreads();
    if (k0 + 64 < K) {
      Ap += 64; Bp += 64;
      a0 = *(const s8v*)Ap; a1 = *(const s8v*)(Ap + 8);
      b0 = *(const s8v*)Bp; b1 = *(const s8v*)(Bp + 8);
    }
    mfma_tile(As, Bs, wr, wc, l, acc);
    __syncthreads();
  }
  asm volatile("s_nop 7\n\ts_nop 7");
  int lr = l & 15, lg4 = (l >> 4) * 4;
#pragma unroll
  for (int fi = 0; fi < 2; ++fi)
#pragma unroll
    for (int fj = 0; fj < 2; ++fj) {
      f32x4 v = acc[fi][fj];
#pragma unroll
      for (int r = 0; r < 4; ++r) {
        int row = row0 + wr + fi * 16 + lg4 + r;
        int c = c0 + wc + fj * 16 + lr;
        float vv = v[r];
        size_t o = (size_t)row * DD + c;
        if (region == 0) {
          float s = 1.f / (1.f + __expf(-(vv + br[c])));
          rnH[o] = f2bf(s * nodes[o]);
        } else if (region == 1) {
          zb[o] = 1.f / (1.f + __expf(-(vv + bz[c])));
        } else {
          Hpre[o] = vv;
        }
      }
    }
}

// ---------------- GEMM2 (pipelined): rn @ WhT[:,1024:] + final gate ----------------
__global__ __launch_bounds__(256) void k_gemm2(const short* __restrict__ rnH,
                                               const short* __restrict__ WT,
                                               const float* __restrict__ bh,
                                               const float* __restrict__ Hpre,
                                               const float* __restrict__ zb,
                                               const float* __restrict__ nodes,
                                               float* __restrict__ out) {
  __shared__ __align__(16) short As[64 * 72];
  __shared__ __align__(16) short Bs[64 * 72];
  int tid = threadIdx.x;
  int row0 = blockIdx.y * 64;
  int col0 = blockIdx.x * 64;           // [0,512)
  int w = tid >> 6, l = tid & 63;
  int wr = (w >> 1) * 32, wc = (w & 1) * 32;
  int srow = tid >> 2, scc = (tid & 3) * 16;
  const short* Ap = rnH + (size_t)(row0 + srow) * DD + scc;
  const short* Bp = WT + (size_t)2 * (512 * 1536) + (size_t)(col0 + srow) * 1536 + 1024 + scc;
  s8v a0 = *(const s8v*)Ap, a1 = *(const s8v*)(Ap + 8);
  s8v b0 = *(const s8v*)Bp, b1 = *(const s8v*)(Bp + 8);
  f32x4 acc[2][2] = {};
  for (int k0 = 0; k0 < DD; k0 += 64) {
    *(s8v*)&As[srow * 72 + scc] = a0; *(s8v*)&As[srow * 72 + scc + 8] = a1;
    *(s8v*)&Bs[srow * 72 + scc] = b0; *(s8v*)&Bs[srow * 72 + scc + 8] = b1;
    __syncthreads();
    if (k0 + 64 < DD) {
      Ap += 64; Bp += 64;
      a0 = *(const s8v*)Ap; a1 = *(const s8v*)(Ap + 8);
      b0 = *(const s8v*)Bp; b1 = *(const s8v*)(Bp + 8);
    }
    mfma_tile(As, Bs, wr, wc, l, acc);
    __syncthreads();
  }
  asm volatile("s_nop 7\n\ts_nop 7");
  int lr = l & 15, lg4 = (l >> 4) * 4;
#pragma unroll
  for (int fi = 0; fi < 2; ++fi)
#pragma unroll
    for (int fj = 0; fj < 2; ++fj) {
      f32x4 v = acc[fi][fj];
#pragma unroll
      for (int r = 0; r < 4; ++r) {
        int row = row0 + wr + fi * 16 + lg4 + r;
        int c = col0 + wc + fj * 16 + lr;
        size_t o = (size_t)row * DD + c;
        float h = tanhf(v[r] + Hpre[o] + bh[c]);
        float zz = zb[o];
        float nd = nodes[o];
        out[o] = (1.f - zz) * nd + zz * h;
      }
    }
}

extern "C" void kernel_launch(void* const* d_in, const int* in_sizes, int n_in,
                              void* d_out, int out_size, void* d_ws, size_t ws_size,
                              hipStream_t stream) {
  const float* nodes = (const float*)d_in[0];
  const float* edges = (const float*)d_in[1];
  const int* adj_in = (const int*)d_in[2];
  const int* adj_out = (const int*)d_in[3];
  const void* exist_in = d_in[4];
  const void* exist_out = d_in[5];
  const float* Wa_in = (const float*)d_in[6];
  const float* ba_in = (const float*)d_in[7];
  const float* Wa_out = (const float*)d_in[8];
  const float* ba_out = (const float*)d_in[9];
  const float* Wr = (const float*)d_in[10];
  const float* br = (const float*)d_in[11];
  const float* Wz = (const float*)d_in[12];
  const float* bz = (const float*)d_in[13];
  const float* Wh = (const float*)d_in[14];
  const float* bh = (const float*)d_in[15];

  char* ws = (char*)d_ws;
  int* flags = (int*)ws;
  float* projp = (float*)(ws + WS_PROJP);
  short* nodesH = (short*)(ws + WS_NODESH);
  short* allmsgsH = (short*)(ws + WS_ALLMSGS);
  short* AcatH = (short*)(ws + WS_ACAT);
  short* edgesT = (short*)(ws + WS_EDGEST);
  short* WT = (short*)(ws + WS_WT);
  short* rnH = (short*)(ws + WS_RN);
  float* zb = (float*)(ws + WS_ZB);
  float* Hpre = (float*)(ws + WS_HPRE);
  float* out = (float*)d_out;

  k_prep<<<dim3(16, 48, 12), 256, 0, stream>>>(edges, Wr, Wz, Wh, nodes,
                                               exist_in, exist_out, edgesT, WT,
                                               nodesH, AcatH, flags);
  k_gemm_msgs<<<dim3(64, 12), 256, 0, stream>>>(nodesH, edgesT, Wa_in, Wa_out,
                                                allmsgsH, projp);
  k_attn<<<2 * ROWS, 256, 0, stream>>>(allmsgsH, projp, adj_in, adj_out,
                                       exist_in, exist_out, flags, nodes,
                                       Wa_in, ba_in, Wa_out, ba_out, AcatH);
  k_gemm1<<<dim3(24, 12), 256, 0, stream>>>(AcatH, WT, br, bz, nodes, rnH, zb,
                                            Hpre);
  k_gemm2<<<dim3(8, 12), 256, 0, stream>>>(rnH, WT, bh, Hpre, zb, nodes, out);
}